// Round 2
// baseline (2051.228 us; speedup 1.0000x reference)
//
#include <hip/hip_runtime.h>
#include <hip/hip_bf16.h>

#define BATCH 4
#define SEQ 2048
#define HEADS 16
#define DHEAD 64
#define HID 1024
#define MROWS (BATCH * SEQ)   // 8192

typedef unsigned short u16;
typedef unsigned int u32;

// bf16 (low/high half of a packed u32) -> f32, exact
__device__ __forceinline__ float bflo(u32 w) { union { u32 i; float f; } x; x.i = w << 16; return x.f; }
__device__ __forceinline__ float bfhi(u32 w) { union { u32 i; float f; } x; x.i = w & 0xffff0000u; return x.f; }
// f32 -> bf16 round-to-nearest-even (inputs finite)
__device__ __forceinline__ u16 f2bf(float f) {
  union { float f; u32 i; } x; x.f = f;
  u32 r = x.i + 0x7fffu + ((x.i >> 16) & 1u);
  return (u16)(r >> 16);
}

// C[M,N] = X[M,K] @ W[N,K]^T + bias.  X is fp32 (XBF=false) or bf16 ws (XBF=true).
// W,Bias fp32.  Out: SPLIT=true -> bf16 ws in [B,HEADS,SEQ,DHEAD]; else fp32 [M,N].
// M=8192, N=K=1024.  Tile 64x64x32, 256 threads, 4x4 micro-tile, fp32 accum.
// LDS is k-major ([kk][row], pad 68) so the inner loop is an outer product with
// conflict-free ds_read_b128.
template<bool XBF, bool SPLIT>
__global__ __launch_bounds__(256) void gemm64(
    const void* __restrict__ Xv, const float* __restrict__ W,
    const float* __restrict__ Bias, void* __restrict__ Outv)
{
  __shared__ float Xsk[32][68];
  __shared__ float Wsk[32][68];
  const int tid = threadIdx.x;
  const int m0 = blockIdx.x << 6;
  const int n0 = blockIdx.y << 6;
  const int ty = tid >> 4, tx = tid & 15;
  const int lrow = tid >> 2;        // 0..63
  const int lc8  = (tid & 3) << 3;  // 0,8,16,24 (k chunk of 8 elements)

  float acc[4][4] = {{0.f, 0.f, 0.f, 0.f}, {0.f, 0.f, 0.f, 0.f},
                     {0.f, 0.f, 0.f, 0.f}, {0.f, 0.f, 0.f, 0.f}};

  const float* wp = W + (size_t)(n0 + lrow) * HID + lc8;

  for (int k0 = 0; k0 < HID; k0 += 32) {
    // stage X tile, k-major
    if (XBF) {
      const u16* xp = (const u16*)Xv + (size_t)(m0 + lrow) * HID + lc8 + k0;
      const uint4 xr = *(const uint4*)xp;  // 8 bf16
      Xsk[lc8 + 0][lrow] = bflo(xr.x); Xsk[lc8 + 1][lrow] = bfhi(xr.x);
      Xsk[lc8 + 2][lrow] = bflo(xr.y); Xsk[lc8 + 3][lrow] = bfhi(xr.y);
      Xsk[lc8 + 4][lrow] = bflo(xr.z); Xsk[lc8 + 5][lrow] = bfhi(xr.z);
      Xsk[lc8 + 6][lrow] = bflo(xr.w); Xsk[lc8 + 7][lrow] = bfhi(xr.w);
    } else {
      const float* xp = (const float*)Xv + (size_t)(m0 + lrow) * HID + lc8 + k0;
      const float4 a = *(const float4*)xp;
      const float4 b = *(const float4*)(xp + 4);
      Xsk[lc8 + 0][lrow] = a.x; Xsk[lc8 + 1][lrow] = a.y;
      Xsk[lc8 + 2][lrow] = a.z; Xsk[lc8 + 3][lrow] = a.w;
      Xsk[lc8 + 4][lrow] = b.x; Xsk[lc8 + 5][lrow] = b.y;
      Xsk[lc8 + 6][lrow] = b.z; Xsk[lc8 + 7][lrow] = b.w;
    }
    { // stage W tile, k-major (fp32)
      const float4 a = *(const float4*)(wp + k0);
      const float4 b = *(const float4*)(wp + k0 + 4);
      Wsk[lc8 + 0][lrow] = a.x; Wsk[lc8 + 1][lrow] = a.y;
      Wsk[lc8 + 2][lrow] = a.z; Wsk[lc8 + 3][lrow] = a.w;
      Wsk[lc8 + 4][lrow] = b.x; Wsk[lc8 + 5][lrow] = b.y;
      Wsk[lc8 + 6][lrow] = b.z; Wsk[lc8 + 7][lrow] = b.w;
    }
    __syncthreads();
    #pragma unroll 8
    for (int kk = 0; kk < 32; ++kk) {
      const float4 xa = *(const float4*)&Xsk[kk][ty << 2];
      const float4 wb = *(const float4*)&Wsk[kk][tx << 2];
      const float xv[4] = {xa.x, xa.y, xa.z, xa.w};
      const float wv[4] = {wb.x, wb.y, wb.z, wb.w};
      #pragma unroll
      for (int i = 0; i < 4; ++i)
        #pragma unroll
        for (int j = 0; j < 4; ++j)
          acc[i][j] = fmaf(xv[i], wv[j], acc[i][j]);
    }
    __syncthreads();
  }

  const int nb = n0 + (tx << 2);
  const float4 bv = *(const float4*)(Bias + nb);
  #pragma unroll
  for (int i = 0; i < 4; ++i) {
    const int m = m0 + (ty << 2) + i;
    const float r0 = acc[i][0] + bv.x, r1 = acc[i][1] + bv.y;
    const float r2 = acc[i][2] + bv.z, r3 = acc[i][3] + bv.w;
    if (SPLIT) {
      const int b = m >> 11, s = m & (SEQ - 1);
      const int h = nb >> 6, d = nb & 63;
      const size_t idx = (((size_t)(b * HEADS + h)) * SEQ + s) * DHEAD + d;
      ushort4 pk;
      pk.x = f2bf(r0); pk.y = f2bf(r1); pk.z = f2bf(r2); pk.w = f2bf(r3);
      *(ushort4*)((u16*)Outv + idx) = pk;
    } else {
      const size_t idx = (size_t)m * HID + nb;
      *(float4*)((float*)Outv + idx) = make_float4(r0, r1, r2, r3);
    }
  }
}

// Flash attention over [B,H,S,64] bf16 ws. One block per (bh, 64-query tile).
// Online softmax, fp32 accum. Masked QUERY rows -> all logits -1e9 -> uniform
// softmax (matches reference semantics exactly). Writes hidden [B,S,HID] bf16.
__global__ __launch_bounds__(256) void attn64(
    const u16* __restrict__ QH, const u16* __restrict__ KH,
    const u16* __restrict__ VH, const int* __restrict__ Mask,
    u16* __restrict__ Hidden)
{
  __shared__ float Qd[DHEAD][68];  // [dim][qrow], pre-scaled by 1/8
  __shared__ float Kd[DHEAD][68];  // [dim][key]
  __shared__ float Vs[64][68];     // [key][dim]
  __shared__ float Ps[64][68];     // [key][qrow]

  const int tid = threadIdx.x;
  const int ty = tid >> 4, tx = tid & 15;
  const int lrow = tid >> 2;        // 0..63
  const int lcb  = (tid & 3) << 4;  // 0,16,32,48 (16 dims = 32B)

  const int bh = blockIdx.y;        // b*16+h
  const int b  = bh >> 4;
  const int h  = bh & 15;
  const int q0 = blockIdx.x << 6;

  const size_t hb = (size_t)bh * SEQ * DHEAD;

  { // stage Q (scaled by 1/sqrt(dh)=0.125), transposed to [dim][row]
    const u16* qp = QH + hb + (size_t)(q0 + lrow) * DHEAD + lcb;
    const uint4 a = *(const uint4*)qp;
    const uint4 c = *(const uint4*)(qp + 8);
    const float s = 0.125f;
    Qd[lcb +  0][lrow] = bflo(a.x) * s; Qd[lcb +  1][lrow] = bfhi(a.x) * s;
    Qd[lcb +  2][lrow] = bflo(a.y) * s; Qd[lcb +  3][lrow] = bfhi(a.y) * s;
    Qd[lcb +  4][lrow] = bflo(a.z) * s; Qd[lcb +  5][lrow] = bfhi(a.z) * s;
    Qd[lcb +  6][lrow] = bflo(a.w) * s; Qd[lcb +  7][lrow] = bfhi(a.w) * s;
    Qd[lcb +  8][lrow] = bflo(c.x) * s; Qd[lcb +  9][lrow] = bfhi(c.x) * s;
    Qd[lcb + 10][lrow] = bflo(c.y) * s; Qd[lcb + 11][lrow] = bfhi(c.y) * s;
    Qd[lcb + 12][lrow] = bflo(c.z) * s; Qd[lcb + 13][lrow] = bfhi(c.z) * s;
    Qd[lcb + 14][lrow] = bflo(c.w) * s; Qd[lcb + 15][lrow] = bfhi(c.w) * s;
  }
  bool valid[4];
  #pragma unroll
  for (int i = 0; i < 4; ++i)
    valid[i] = Mask[b * SEQ + q0 + (ty << 2) + i] != 0;

  float mr[4] = {-__builtin_inff(), -__builtin_inff(), -__builtin_inff(), -__builtin_inff()};
  float lr[4] = {0.f, 0.f, 0.f, 0.f};
  float o[4][4] = {{0.f, 0.f, 0.f, 0.f}, {0.f, 0.f, 0.f, 0.f},
                   {0.f, 0.f, 0.f, 0.f}, {0.f, 0.f, 0.f, 0.f}};

  for (int t0 = 0; t0 < SEQ; t0 += 64) {
    __syncthreads();  // Q staged (iter 0) / prior PV reads of Kd,Vs,Ps done
    { // stage K transposed [dim][key], V natural [key][dim]
      const u16* kp = KH + hb + (size_t)(t0 + lrow) * DHEAD + lcb;
      const uint4 a = *(const uint4*)kp;
      const uint4 c = *(const uint4*)(kp + 8);
      Kd[lcb +  0][lrow] = bflo(a.x); Kd[lcb +  1][lrow] = bfhi(a.x);
      Kd[lcb +  2][lrow] = bflo(a.y); Kd[lcb +  3][lrow] = bfhi(a.y);
      Kd[lcb +  4][lrow] = bflo(a.z); Kd[lcb +  5][lrow] = bfhi(a.z);
      Kd[lcb +  6][lrow] = bflo(a.w); Kd[lcb +  7][lrow] = bfhi(a.w);
      Kd[lcb +  8][lrow] = bflo(c.x); Kd[lcb +  9][lrow] = bfhi(c.x);
      Kd[lcb + 10][lrow] = bflo(c.y); Kd[lcb + 11][lrow] = bfhi(c.y);
      Kd[lcb + 12][lrow] = bflo(c.z); Kd[lcb + 13][lrow] = bfhi(c.z);
      Kd[lcb + 14][lrow] = bflo(c.w); Kd[lcb + 15][lrow] = bfhi(c.w);
      const u16* vp = VH + hb + (size_t)(t0 + lrow) * DHEAD + lcb;
      const uint4 va = *(const uint4*)vp;
      const uint4 vc = *(const uint4*)(vp + 8);
      *(float4*)&Vs[lrow][lcb +  0] = make_float4(bflo(va.x), bfhi(va.x), bflo(va.y), bfhi(va.y));
      *(float4*)&Vs[lrow][lcb +  4] = make_float4(bflo(va.z), bfhi(va.z), bflo(va.w), bfhi(va.w));
      *(float4*)&Vs[lrow][lcb +  8] = make_float4(bflo(vc.x), bfhi(vc.x), bflo(vc.y), bfhi(vc.y));
      *(float4*)&Vs[lrow][lcb + 12] = make_float4(bflo(vc.z), bfhi(vc.z), bflo(vc.w), bfhi(vc.w));
    }
    __syncthreads();

    float sc[4][4] = {{0.f, 0.f, 0.f, 0.f}, {0.f, 0.f, 0.f, 0.f},
                      {0.f, 0.f, 0.f, 0.f}, {0.f, 0.f, 0.f, 0.f}};
    #pragma unroll 8
    for (int d = 0; d < DHEAD; ++d) {
      const float4 qa = *(const float4*)&Qd[d][ty << 2];
      const float4 kb = *(const float4*)&Kd[d][tx << 2];
      const float qv[4] = {qa.x, qa.y, qa.z, qa.w};
      const float kv[4] = {kb.x, kb.y, kb.z, kb.w};
      #pragma unroll
      for (int i = 0; i < 4; ++i)
        #pragma unroll
        for (int j = 0; j < 4; ++j)
          sc[i][j] = fmaf(qv[i], kv[j], sc[i][j]);
    }

    #pragma unroll
    for (int i = 0; i < 4; ++i) {
      if (!valid[i]) { sc[i][0] = -1e9f; sc[i][1] = -1e9f; sc[i][2] = -1e9f; sc[i][3] = -1e9f; }
      float mx = fmaxf(fmaxf(sc[i][0], sc[i][1]), fmaxf(sc[i][2], sc[i][3]));
      #pragma unroll
      for (int off = 1; off < 16; off <<= 1)
        mx = fmaxf(mx, __shfl_xor(mx, off));
      const float mnew  = fmaxf(mr[i], mx);
      const float alpha = __expf(mr[i] - mnew);
      float ps = 0.f;
      #pragma unroll
      for (int j = 0; j < 4; ++j) {
        const float p = __expf(sc[i][j] - mnew);
        sc[i][j] = p; ps += p;
      }
      #pragma unroll
      for (int off = 1; off < 16; off <<= 1)
        ps += __shfl_xor(ps, off);
      lr[i] = lr[i] * alpha + ps;
      mr[i] = mnew;
      #pragma unroll
      for (int j = 0; j < 4; ++j) {
        o[i][j] *= alpha;
        Ps[(tx << 2) + j][(ty << 2) + i] = sc[i][j];  // [key][qrow]
      }
    }
    __syncthreads();

    #pragma unroll 8
    for (int kk = 0; kk < 64; ++kk) {
      const float4 pa = *(const float4*)&Ps[kk][ty << 2];
      const float4 vb = *(const float4*)&Vs[kk][tx << 2];
      const float pv[4] = {pa.x, pa.y, pa.z, pa.w};
      const float vv[4] = {vb.x, vb.y, vb.z, vb.w};
      #pragma unroll
      for (int i = 0; i < 4; ++i)
        #pragma unroll
        for (int j = 0; j < 4; ++j)
          o[i][j] = fmaf(pv[i], vv[j], o[i][j]);
    }
  }

  #pragma unroll
  for (int i = 0; i < 4; ++i) {
    const float inv = 1.f / lr[i];
    const int srow = q0 + (ty << 2) + i;
    ushort4 pk;
    pk.x = f2bf(o[i][0] * inv);
    pk.y = f2bf(o[i][1] * inv);
    pk.z = f2bf(o[i][2] * inv);
    pk.w = f2bf(o[i][3] * inv);
    *(ushort4*)(Hidden + (size_t)(b * SEQ + srow) * HID + h * DHEAD + (tx << 2)) = pk;
  }
}

extern "C" void kernel_launch(void* const* d_in, const int* in_sizes, int n_in,
                              void* d_out, int out_size, void* d_ws, size_t ws_size,
                              hipStream_t stream) {
  const float* q  = (const float*)d_in[0];   // fp32, per reference dtypes
  const float* k  = (const float*)d_in[1];
  const float* v  = (const float*)d_in[2];
  const int* mask = (const int*)d_in[3];
  const float* wq = (const float*)d_in[4];
  const float* bq = (const float*)d_in[5];
  const float* wk = (const float*)d_in[6];
  const float* bk = (const float*)d_in[7];
  const float* wv = (const float*)d_in[8];
  const float* bv = (const float*)d_in[9];
  const float* wo = (const float*)d_in[10];
  const float* bo = (const float*)d_in[11];

  // ws: qh | kh | vh ([B,H,S,64] bf16) | hidden ([B,S,HID] bf16) = 64 MiB
  const size_t seg = (size_t)MROWS * HID;  // 8388608 elements
  u16* qh     = (u16*)d_ws;
  u16* kh     = qh + seg;
  u16* vh     = kh + seg;
  u16* hidden = vh + seg;

  const dim3 gg(MROWS / 64, HID / 64);
  gemm64<false, true><<<gg, 256, 0, stream>>>(q, wq, bq, qh);
  gemm64<false, true><<<gg, 256, 0, stream>>>(k, wk, bk, kh);
  gemm64<false, true><<<gg, 256, 0, stream>>>(v, wv, bv, vh);
  attn64<<<dim3(SEQ / 64, BATCH * HEADS), 256, 0, stream>>>(qh, kh, vh, mask, hidden);
  gemm64<true, false><<<gg, 256, 0, stream>>>(hidden, wo, bo, (float*)d_out);
}

// Round 3
// 505.024 us; speedup vs baseline: 4.0616x; 4.0616x over previous
//
#include <hip/hip_runtime.h>

#define BATCH 4
#define SEQ 2048
#define HEADS 16
#define DHEAD 64
#define HID 1024
#define MROWS (BATCH * SEQ)   // 8192

typedef unsigned short u16;
typedef unsigned int u32;
typedef __attribute__((ext_vector_type(4))) float f32x4;
typedef __attribute__((ext_vector_type(8))) short bf16x8;

#define MFMA16(a, b, c) __builtin_amdgcn_mfma_f32_16x16x32_bf16((a), (b), (c), 0, 0, 0)

// f32 -> bf16 round-to-nearest-even (finite inputs)
__device__ __forceinline__ u16 f2bf(float f) {
  union { float f; u32 i; } x; x.f = f;
  u32 r = x.i + 0x7fffu + ((x.i >> 16) & 1u);
  return (u16)(r >> 16);
}

// async global->LDS, 16 B per lane.  LDS dest must be wave-uniform base + lane*16.
__device__ __forceinline__ void lds16(const u16* g, u16* s) {
  __builtin_amdgcn_global_load_lds(
      (const __attribute__((address_space(1))) void*)g,
      (__attribute__((address_space(3))) void*)s, 16, 0, 0);
}

// VALU staging: 8 fp32 -> 8 bf16 into LDS (plan-B fallback path)
__device__ __forceinline__ void stage8f(const float* __restrict__ g, u16* s) {
  const float4 a = *(const float4*)g;
  const float4 b = *(const float4*)(g + 4);
  ushort4 lo, hi;
  lo.x = f2bf(a.x); lo.y = f2bf(a.y); lo.z = f2bf(a.z); lo.w = f2bf(a.w);
  hi.x = f2bf(b.x); hi.y = f2bf(b.y); hi.z = f2bf(b.z); hi.w = f2bf(b.w);
  *(ushort4*)s = lo;
  *(ushort4*)(s + 4) = hi;
}

// elementwise fp32 -> bf16 (memory-bound, ~30 us total)
__global__ __launch_bounds__(256) void cvt_bf16(
    const float* __restrict__ in, u16* __restrict__ out, int n) {
  const int i = (blockIdx.x * 256 + threadIdx.x) * 8;
  if (i >= n) return;
  stage8f(in + i, out + i);
}

// C[M,N] = A[M,K] @ W[N,K]^T + bias, MFMA 16x16x32 bf16, fp32 accum.
// M=8192, N=K=1024.  Tile 128x128, BK=32, 256 threads = 4 waves (2x2 of 64x64),
// each wave 4x4 MFMA tiles.  m97 2-barrier K-loop.
// ADMA/BDMA: operand is bf16, stage via global_load_lds; else fp32, VALU-convert.
// OUTMODE: 0 = fp32 [M,N]; 1 = bf16 [bh][s][64] (qh/kh, *oscale); 2 = bf16 [bh][d][s] (v^T).
template<bool ADMA, bool BDMA, int OUTMODE>
__global__ __launch_bounds__(256) void gemm_bt(
    const void* __restrict__ Av, const void* __restrict__ Wv,
    const float* __restrict__ Bias, void* __restrict__ Outv, float oscale)
{
  __shared__ u16 As[128 * 32];
  __shared__ u16 Bs[128 * 32];
  const int tid = threadIdx.x;
  const int m0 = blockIdx.x << 7;
  const int n0 = blockIdx.y << 7;
  const int w = tid >> 6, l = tid & 63;
  const int quad = l >> 4, l15 = l & 15;
  const int wm = (w & 1) << 6, wn = (w >> 1) << 6;
  const int srow = tid >> 2;          // 0..63
  const int schunk = (tid & 3) << 3;  // 0,8,16,24

  f32x4 acc[4][4] = {};

  for (int k0 = 0; k0 < HID; k0 += 32) {
    if (ADMA) {
      const u16* ag = (const u16*)Av + (size_t)(m0 + srow) * HID + k0 + schunk;
      lds16(ag, &As[tid * 8]);
      lds16(ag + (size_t)64 * HID, &As[2048 + tid * 8]);
    } else {
      const float* ag = (const float*)Av + (size_t)(m0 + srow) * HID + k0 + schunk;
      stage8f(ag, &As[srow * 32 + schunk]);
      stage8f(ag + (size_t)64 * HID, &As[(64 + srow) * 32 + schunk]);
    }
    if (BDMA) {
      const u16* bg = (const u16*)Wv + (size_t)(n0 + srow) * HID + k0 + schunk;
      lds16(bg, &Bs[tid * 8]);
      lds16(bg + (size_t)64 * HID, &Bs[2048 + tid * 8]);
    } else {
      const float* bg = (const float*)Wv + (size_t)(n0 + srow) * HID + k0 + schunk;
      stage8f(bg, &Bs[srow * 32 + schunk]);
      stage8f(bg + (size_t)64 * HID, &Bs[(64 + srow) * 32 + schunk]);
    }
    __syncthreads();

    bf16x8 a[4], b[4];
    #pragma unroll
    for (int i = 0; i < 4; ++i)
      a[i] = *(const bf16x8*)&As[(wm + i * 16 + l15) * 32 + quad * 8];
    #pragma unroll
    for (int j = 0; j < 4; ++j)
      b[j] = *(const bf16x8*)&Bs[(wn + j * 16 + l15) * 32 + quad * 8];
    #pragma unroll
    for (int i = 0; i < 4; ++i)
      #pragma unroll
      for (int j = 0; j < 4; ++j)
        acc[i][j] = MFMA16(a[i], b[j], acc[i][j]);
    __syncthreads();
  }

  // epilogue.  C/D layout: col n = l15 (+16j), row m = quad*4 + r (+16i).
  #pragma unroll
  for (int j = 0; j < 4; ++j) {
    const int n = n0 + wn + j * 16 + l15;
    const float bias = Bias[n];
    #pragma unroll
    for (int i = 0; i < 4; ++i) {
      const int mb = m0 + wm + i * 16 + (quad << 2);
      if (OUTMODE == 0) {
        float* Out = (float*)Outv;
        #pragma unroll
        for (int r = 0; r < 4; ++r)
          Out[(size_t)(mb + r) * HID + n] = acc[i][j][r] + bias;
      } else if (OUTMODE == 1) {
        u16* Out = (u16*)Outv;
        const int h = n >> 6, d = n & 63;
        #pragma unroll
        for (int r = 0; r < 4; ++r) {
          const int m = mb + r;
          const int bb = m >> 11, s = m & (SEQ - 1);
          Out[((size_t)(bb * HEADS + h) * SEQ + s) * DHEAD + d] =
              f2bf((acc[i][j][r] + bias) * oscale);
        }
      } else {  // 2: v transposed [bh][d][s]
        u16* Out = (u16*)Outv;
        const int h = n >> 6, d = n & 63;
        const int bb = mb >> 11, s0 = mb & (SEQ - 1);
        ushort4 pk;
        pk.x = f2bf(acc[i][j][0] + bias);
        pk.y = f2bf(acc[i][j][1] + bias);
        pk.z = f2bf(acc[i][j][2] + bias);
        pk.w = f2bf(acc[i][j][3] + bias);
        *(ushort4*)&Out[((size_t)(bb * HEADS + h) * DHEAD + d) * SEQ + s0] = pk;
      }
    }
  }
}

// Flash attention, MFMA.  qh [bh][s][64] (pre-scaled by 1/8), kh [bh][s][64],
// vt [bh][d][s], all bf16.  Block = 256 thr = 4 waves; wave w owns query rows
// w*16..w*16+15 of a 64-query tile.  Per 64-key tile: QK^T (8 MFMA) -> online
// softmax in C-layout -> P to LDS bf16 -> PV (8 MFMA).  Masked query rows:
// logits *= 0 -> uniform softmax == reference.  Writes hidden [B,S,1024] bf16.
__global__ __launch_bounds__(256) void attn_mfma(
    const u16* __restrict__ QH, const u16* __restrict__ KH,
    const u16* __restrict__ VT, const int* __restrict__ Mask,
    u16* __restrict__ Hidden)
{
  __shared__ u16 Qs[2][64 * 32];   // half hh: Q[q][hh*32+d] as [q][32]
  __shared__ u16 Ks[2][64 * 32];   // half hh: K[key][hh*32+d] as [key][32]
  __shared__ u16 Vt[2][64 * 32];   // half hh: V^T[d][hh*32+key] as [d][32]
  __shared__ u16 Ps[64 * 76];      // P[q][key], pad 76 (152 B = 38 banks)

  const int tid = threadIdx.x;
  const int w = tid >> 6, l = tid & 63;
  const int quad = l >> 4, l15 = l & 15;
  const int bh = blockIdx.y, b = bh >> 4, h = bh & 15;
  const int q0 = blockIdx.x << 6;
  const int srow = tid >> 2, schunk = (tid & 3) << 3;

  const u16* qbase = QH + (size_t)bh * SEQ * DHEAD;
  const u16* kbase = KH + (size_t)bh * SEQ * DHEAD;
  const u16* vbase = VT + (size_t)bh * DHEAD * SEQ;

  // stage Q once (drained by first in-loop barrier)
  #pragma unroll
  for (int hh = 0; hh < 2; ++hh)
    lds16(qbase + (size_t)(q0 + srow) * DHEAD + hh * 32 + schunk, &Qs[hh][tid * 8]);

  float flag[4];
  #pragma unroll
  for (int r = 0; r < 4; ++r)
    flag[r] = (Mask[b * SEQ + q0 + w * 16 + (quad << 2) + r] != 0) ? 1.f : 0.f;

  float mrow[4] = {-1e30f, -1e30f, -1e30f, -1e30f};
  float lrow[4] = {0.f, 0.f, 0.f, 0.f};
  f32x4 o[4] = {};

  for (int t0 = 0; t0 < SEQ; t0 += 64) {
    __syncthreads();  // prior-iter LDS reads done before restage
    #pragma unroll
    for (int hh = 0; hh < 2; ++hh) {
      lds16(kbase + (size_t)(t0 + srow) * DHEAD + hh * 32 + schunk, &Ks[hh][tid * 8]);
      lds16(vbase + (size_t)srow * SEQ + t0 + hh * 32 + schunk, &Vt[hh][tid * 8]);
    }
    __syncthreads();  // staging (incl. Q on iter 0) visible

    // S = Q K^T  (Q pre-scaled by 1/8)
    f32x4 s[4] = {};
    #pragma unroll
    for (int hh = 0; hh < 2; ++hh) {
      const bf16x8 aq = *(const bf16x8*)&Qs[hh][(w * 16 + l15) * 32 + quad * 8];
      #pragma unroll
      for (int j = 0; j < 4; ++j)
        s[j] = MFMA16(aq, *(const bf16x8*)&Ks[hh][(j * 16 + l15) * 32 + quad * 8], s[j]);
    }

    // online softmax, rows quad*4+r; key-reduction: 4 tiles in-reg + 16-lane shfl
    #pragma unroll
    for (int r = 0; r < 4; ++r) {
      float p0 = s[0][r] * flag[r], p1 = s[1][r] * flag[r];
      float p2 = s[2][r] * flag[r], p3 = s[3][r] * flag[r];
      float mx = fmaxf(fmaxf(p0, p1), fmaxf(p2, p3));
      #pragma unroll
      for (int off = 1; off < 16; off <<= 1)
        mx = fmaxf(mx, __shfl_xor(mx, off));
      const float mnew = fmaxf(mrow[r], mx);
      const float alpha = __expf(mrow[r] - mnew);
      p0 = __expf(p0 - mnew); p1 = __expf(p1 - mnew);
      p2 = __expf(p2 - mnew); p3 = __expf(p3 - mnew);
      float ps = p0 + p1 + p2 + p3;
      #pragma unroll
      for (int off = 1; off < 16; off <<= 1)
        ps += __shfl_xor(ps, off);
      lrow[r] = lrow[r] * alpha + ps;
      mrow[r] = mnew;
      #pragma unroll
      for (int j = 0; j < 4; ++j) o[j][r] *= alpha;
      const int prow = (w * 16 + (quad << 2) + r) * 76;
      Ps[prow + l15]      = f2bf(p0);
      Ps[prow + 16 + l15] = f2bf(p1);
      Ps[prow + 32 + l15] = f2bf(p2);
      Ps[prow + 48 + l15] = f2bf(p3);
    }
    // wave-private Ps rows: no cross-wave hazard; compiler orders write->read.

    // O += P V
    #pragma unroll
    for (int hh = 0; hh < 2; ++hh) {
      const bf16x8 ap = *(const bf16x8*)&Ps[(w * 16 + l15) * 76 + hh * 32 + quad * 8];
      #pragma unroll
      for (int j = 0; j < 4; ++j)
        o[j] = MFMA16(ap, *(const bf16x8*)&Vt[hh][(j * 16 + l15) * 32 + quad * 8], o[j]);
    }
  }

  float inv[4];
  #pragma unroll
  for (int r = 0; r < 4; ++r) inv[r] = 1.f / lrow[r];
  #pragma unroll
  for (int j = 0; j < 4; ++j)
    #pragma unroll
    for (int r = 0; r < 4; ++r) {
      const int srow_g = q0 + w * 16 + (quad << 2) + r;
      Hidden[((size_t)(b * SEQ + srow_g)) * HID + h * DHEAD + j * 16 + l15] =
          f2bf(o[j][r] * inv[r]);
    }
}

extern "C" void kernel_launch(void* const* d_in, const int* in_sizes, int n_in,
                              void* d_out, int out_size, void* d_ws, size_t ws_size,
                              hipStream_t stream) {
  const float* q  = (const float*)d_in[0];
  const float* k  = (const float*)d_in[1];
  const float* v  = (const float*)d_in[2];
  const int* mask = (const int*)d_in[3];
  const float* wq = (const float*)d_in[4];
  const float* bq = (const float*)d_in[5];
  const float* wk = (const float*)d_in[6];
  const float* bk = (const float*)d_in[7];
  const float* wv = (const float*)d_in[8];
  const float* bv = (const float*)d_in[9];
  const float* wo = (const float*)d_in[10];
  const float* bo = (const float*)d_in[11];

  const size_t SEG = (size_t)MROWS * HID;    // 8388608 elements
  const size_t WSEG = (size_t)HID * HID;     // 1048576
  const dim3 gg(MROWS / 128, HID / 128);     // 64 x 8
  const dim3 ga(SEQ / 64, BATCH * HEADS);    // 32 x 64
  const float qscale = 0.125f;               // 1/sqrt(64), exact in bf16

  const size_t planA_bytes = (4 * WSEG + 4 * SEG) * sizeof(u16);  // 75.5 MB
  if (ws_size >= planA_bytes) {
    // plan A: pre-convert weights+inputs to bf16, all-DMA GEMMs
    u16* wqb  = (u16*)d_ws;
    u16* wkb  = wqb + WSEG;
    u16* wvb  = wkb + WSEG;
    u16* wob  = wvb + WSEG;
    u16* xbuf = wob + WSEG;        // reused: xq -> xk -> xv -> hidden
    u16* qh   = xbuf + SEG;
    u16* kh   = qh + SEG;
    u16* vt   = kh + SEG;

    cvt_bf16<<<WSEG / 2048, 256, 0, stream>>>(wq, wqb, (int)WSEG);
    cvt_bf16<<<WSEG / 2048, 256, 0, stream>>>(wk, wkb, (int)WSEG);
    cvt_bf16<<<WSEG / 2048, 256, 0, stream>>>(wv, wvb, (int)WSEG);
    cvt_bf16<<<WSEG / 2048, 256, 0, stream>>>(wo, wob, (int)WSEG);

    cvt_bf16<<<SEG / 2048, 256, 0, stream>>>(q, xbuf, (int)SEG);
    gemm_bt<true, true, 1><<<gg, 256, 0, stream>>>(xbuf, wqb, bq, qh, qscale);
    cvt_bf16<<<SEG / 2048, 256, 0, stream>>>(k, xbuf, (int)SEG);
    gemm_bt<true, true, 1><<<gg, 256, 0, stream>>>(xbuf, wkb, bk, kh, 1.f);
    cvt_bf16<<<SEG / 2048, 256, 0, stream>>>(v, xbuf, (int)SEG);
    gemm_bt<true, true, 2><<<gg, 256, 0, stream>>>(xbuf, wvb, bv, vt, 1.f);

    attn_mfma<<<ga, 256, 0, stream>>>(qh, kh, vt, mask, xbuf /*hidden*/);
    gemm_bt<true, true, 0><<<gg, 256, 0, stream>>>(xbuf, wob, bo, d_out, 1.f);
  } else {
    // plan B: 64 MiB ws — VALU stage-convert fp32 operands inside GEMMs
    u16* qh     = (u16*)d_ws;
    u16* kh     = qh + SEG;
    u16* vt     = kh + SEG;
    u16* hidden = vt + SEG;

    gemm_bt<false, false, 1><<<gg, 256, 0, stream>>>(q, wq, bq, qh, qscale);
    gemm_bt<false, false, 1><<<gg, 256, 0, stream>>>(k, wk, bk, kh, 1.f);
    gemm_bt<false, false, 2><<<gg, 256, 0, stream>>>(v, wv, bv, vt, 1.f);
    attn_mfma<<<ga, 256, 0, stream>>>(qh, kh, vt, mask, hidden);
    gemm_bt<true, false, 0><<<gg, 256, 0, stream>>>(hidden, wo, bo, d_out, 1.f);
  }
}

// Round 4
// 413.353 us; speedup vs baseline: 4.9624x; 1.2218x over previous
//
#include <hip/hip_runtime.h>

#define BATCH 4
#define SEQ 2048
#define HEADS 16
#define DHEAD 64
#define HID 1024
#define MROWS (BATCH * SEQ)   // 8192
#define QSCALE 0.1803368801111092f   // 0.125 * log2(e): exp2 domain

typedef unsigned short u16;
typedef unsigned int u32;
typedef __attribute__((ext_vector_type(4))) float f32x4;
typedef __attribute__((ext_vector_type(8))) short bf16x8;

#define MFMA16(a, b, c) __builtin_amdgcn_mfma_f32_16x16x32_bf16((a), (b), (c), 0, 0, 0)
#define EXP2F(x) __builtin_amdgcn_exp2f(x)

// f32 -> bf16 round-to-nearest-even (finite inputs)
__device__ __forceinline__ u16 f2bf(float f) {
  union { float f; u32 i; } x; x.f = f;
  u32 r = x.i + 0x7fffu + ((x.i >> 16) & 1u);
  return (u16)(r >> 16);
}

// async global->LDS, 16 B/lane.  LDS dest must be wave-uniform base + lane*16.
__device__ __forceinline__ void lds16(const u16* g, u16* s) {
  __builtin_amdgcn_global_load_lds(
      (const __attribute__((address_space(1))) void*)g,
      (__attribute__((address_space(3))) void*)s, 16, 0, 0);
}

// VALU staging: 8 fp32 -> 8 bf16 into LDS
__device__ __forceinline__ void stage8f(const float* __restrict__ g, u16* s) {
  const float4 a = *(const float4*)g;
  const float4 b = *(const float4*)(g + 4);
  ushort4 lo, hi;
  lo.x = f2bf(a.x); lo.y = f2bf(a.y); lo.z = f2bf(a.z); lo.w = f2bf(a.w);
  hi.x = f2bf(b.x); hi.y = f2bf(b.y); hi.z = f2bf(b.z); hi.w = f2bf(b.w);
  *(ushort4*)s = lo;
  *(ushort4*)(s + 4) = hi;
}

// weights fp32 -> bf16, 4 tensors in one launch (grid.y selects)
__global__ __launch_bounds__(256) void cvt4_w(
    const float* __restrict__ a, const float* __restrict__ b,
    const float* __restrict__ c, const float* __restrict__ d,
    u16* __restrict__ oa, u16* __restrict__ ob,
    u16* __restrict__ oc, u16* __restrict__ od, int n) {
  const float* in; u16* out;
  switch (blockIdx.y) {
    case 0: in = a; out = oa; break;
    case 1: in = b; out = ob; break;
    case 2: in = c; out = oc; break;
    default: in = d; out = od; break;
  }
  const int i = (blockIdx.x * 256 + threadIdx.x) * 8;
  if (i < n) stage8f(in + i, out + i);
}

// 128x128x(BK=32) MFMA GEMM core: C = A[M,K] @ W[N,K]^T, fp32 accum.
// A fp32 VALU-staged (ADMA=0) or bf16 DMA (ADMA=1); W likewise per BDMA.
// LDS chunk-slot XOR swizzle (slot = chunk ^ ((row>>1)&3)) -> conflict-free
// ds_read_b128 fragments (2 lanes/bank) while keeping the global_load_lds
// lane->slot contract (wave-uniform base + lane*16).
template<bool ADMA, bool BDMA>
__device__ __forceinline__ void gemm_core(
    const void* __restrict__ Av, const void* __restrict__ Wv,
    int tid, int m0, int n0, u16* As, u16* Bs, f32x4 (&acc)[4][4])
{
  const int srow = tid >> 2, cslot = tid & 3;
  const int gc = cslot ^ ((srow >> 1) & 3);   // swizzled global chunk
  const int w = tid >> 6, l = tid & 63;
  const int quad = l >> 4, l15 = l & 15;
  const int sw = (l15 >> 1) & 3;
  const int wm = (w & 1) << 6, wn = (w >> 1) << 6;

  for (int k0 = 0; k0 < HID; k0 += 32) {
    if (ADMA) {
      const u16* ag = (const u16*)Av + (size_t)(m0 + srow) * HID + k0 + gc * 8;
      lds16(ag, &As[tid * 8]);
      lds16(ag + (size_t)64 * HID, &As[2048 + tid * 8]);
    } else {
      const float* ag = (const float*)Av + (size_t)(m0 + srow) * HID + k0 + gc * 8;
      stage8f(ag, &As[srow * 32 + cslot * 8]);
      stage8f(ag + (size_t)64 * HID, &As[(64 + srow) * 32 + cslot * 8]);
    }
    if (BDMA) {
      const u16* bg = (const u16*)Wv + (size_t)(n0 + srow) * HID + k0 + gc * 8;
      lds16(bg, &Bs[tid * 8]);
      lds16(bg + (size_t)64 * HID, &Bs[2048 + tid * 8]);
    } else {
      const float* bg = (const float*)Wv + (size_t)(n0 + srow) * HID + k0 + gc * 8;
      stage8f(bg, &Bs[srow * 32 + cslot * 8]);
      stage8f(bg + (size_t)64 * HID, &Bs[(64 + srow) * 32 + cslot * 8]);
    }
    __syncthreads();

    bf16x8 a[4], b[4];
    #pragma unroll
    for (int i = 0; i < 4; ++i)
      a[i] = *(const bf16x8*)&As[(wm + i * 16 + l15) * 32 + (quad ^ sw) * 8];
    #pragma unroll
    for (int j = 0; j < 4; ++j)
      b[j] = *(const bf16x8*)&Bs[(wn + j * 16 + l15) * 32 + (quad ^ sw) * 8];
    #pragma unroll
    for (int i = 0; i < 4; ++i)
      #pragma unroll
      for (int j = 0; j < 4; ++j)
        acc[i][j] = MFMA16(a[i], b[j], acc[i][j]);
    __syncthreads();
  }
}

// Fused QKV projection.  blockIdx.z selects q/k/v.  Epilogues:
//  z=0 (Q): *QSCALE and *mask(query row) -> masked rows produce logits 0.
//  z=1 (K): plain bf16 [bh][s][64].
//  z=2 (V): bf16 [bh][d][s] with keys PERMUTED within each 64-group:
//           storage index p of key s0: p = (s0&15)*4 + (s0>>4), matching the
//           attention P-layout so PV A/B fragments read contiguously.
template<bool BDMA>
__global__ __launch_bounds__(256) void gemm_qkv(
    const float* __restrict__ xq, const float* __restrict__ xk,
    const float* __restrict__ xv,
    const void* __restrict__ wqv, const void* __restrict__ wkv,
    const void* __restrict__ wvv,
    const float* __restrict__ bq, const float* __restrict__ bk,
    const float* __restrict__ bv, const int* __restrict__ Mask,
    u16* __restrict__ qh, u16* __restrict__ kh, u16* __restrict__ vt)
{
  __shared__ u16 As[128 * 32];
  __shared__ u16 Bs[128 * 32];
  const int z = blockIdx.z;
  const float* A = (z == 0) ? xq : (z == 1) ? xk : xv;
  const void* W = (z == 0) ? wqv : (z == 1) ? wkv : wvv;
  const float* Bias = (z == 0) ? bq : (z == 1) ? bk : bv;

  const int tid = threadIdx.x;
  const int m0 = blockIdx.x << 7, n0 = blockIdx.y << 7;
  f32x4 acc[4][4] = {};
  gemm_core<false, BDMA>(A, W, tid, m0, n0, As, Bs, acc);

  const int w = tid >> 6, l = tid & 63;
  const int quad = l >> 4, l15 = l & 15;
  const int wm = (w & 1) << 6, wn = (w >> 1) << 6;

  if (z <= 1) {
    u16* Out = (z == 0) ? qh : kh;
    #pragma unroll
    for (int i = 0; i < 4; ++i) {
      float fl[4];
      #pragma unroll
      for (int r = 0; r < 4; ++r) {
        const int m = m0 + wm + i * 16 + (quad << 2) + r;
        fl[r] = (z == 0) ? (Mask[m] ? QSCALE : 0.f) : 1.f;
      }
      #pragma unroll
      for (int j = 0; j < 4; ++j) {
        const int n = n0 + wn + j * 16 + l15;
        const float bias = Bias[n];
        const int h = n >> 6, d = n & 63;
        #pragma unroll
        for (int r = 0; r < 4; ++r) {
          const int m = m0 + wm + i * 16 + (quad << 2) + r;
          const int bb = m >> 11, s = m & (SEQ - 1);
          Out[((size_t)(bb * HEADS + h) * SEQ + s) * DHEAD + d] =
              f2bf((acc[i][j][r] + bias) * fl[r]);
        }
      }
    }
  } else {
    // V^T, key-permuted: within 64-group, key s0 -> slot (quad*4+r)*4 + i
    const int sblk = (m0 + wm) & (SEQ - 1);
    const int bb = (m0 + wm) >> 11;
    #pragma unroll
    for (int j = 0; j < 4; ++j) {
      const int n = n0 + wn + j * 16 + l15;
      const float bias = Bias[n];
      const int h = n >> 6, d = n & 63;
      u16* base = vt + ((size_t)(bb * HEADS + h) * DHEAD + d) * SEQ + sblk;
      #pragma unroll
      for (int r = 0; r < 4; ++r) {
        ushort4 pk;
        pk.x = f2bf(acc[0][j][r] + bias);
        pk.y = f2bf(acc[1][j][r] + bias);
        pk.z = f2bf(acc[2][j][r] + bias);
        pk.w = f2bf(acc[3][j][r] + bias);
        *(ushort4*)(base + ((quad << 2) + r) * 4) = pk;
      }
    }
  }
}

// Output projection: fp32 out = hidden(bf16) @ wo^T + bo
template<bool BDMA>
__global__ __launch_bounds__(256) void gemm_out(
    const u16* __restrict__ hidden, const void* __restrict__ wov,
    const float* __restrict__ bo, float* __restrict__ Out)
{
  __shared__ u16 As[128 * 32];
  __shared__ u16 Bs[128 * 32];
  const int tid = threadIdx.x;
  const int m0 = blockIdx.x << 7, n0 = blockIdx.y << 7;
  f32x4 acc[4][4] = {};
  gemm_core<true, BDMA>(hidden, wov, tid, m0, n0, As, Bs, acc);

  const int w = tid >> 6, l = tid & 63;
  const int quad = l >> 4, l15 = l & 15;
  const int wm = (w & 1) << 6, wn = (w >> 1) << 6;
  #pragma unroll
  for (int j = 0; j < 4; ++j) {
    const int n = n0 + wn + j * 16 + l15;
    const float bias = bo[n];
    #pragma unroll
    for (int i = 0; i < 4; ++i) {
      const int mb = m0 + wm + i * 16 + (quad << 2);
      #pragma unroll
      for (int r = 0; r < 4; ++r)
        Out[(size_t)(mb + r) * HID + n] = acc[i][j][r] + bias;
    }
  }
}

// Flash attention, no-max softmax (scores bounded; masked rows pre-zeroed in Q
// so exp2(0)=1 -> uniform == reference).  128 queries/block, 4 waves of 32x64.
// qh [bh][s][64] pre-scaled by 0.125*log2e; kh [bh][s][64]; vt [bh][d][s] with
// keys permuted per 64-group.  P stored [q][p] (p = l15*4+j), pad 72 -> b64
// writes + conflict-free b128 reads.  Qs/Ks/Vt chunk-XOR swizzled.
__global__ __launch_bounds__(256) void attn_mfma(
    const u16* __restrict__ QH, const u16* __restrict__ KH,
    const u16* __restrict__ VT, u16* __restrict__ Hidden)
{
  __shared__ u16 Qs[2][128 * 32];
  __shared__ u16 Ks[2][64 * 32];
  __shared__ u16 Vt[2][64 * 32];
  __shared__ u16 Ps[128 * 72];

  const int tid = threadIdx.x;
  const int w = tid >> 6, l = tid & 63;
  const int quad = l >> 4, l15 = l & 15;
  const int sw = (l15 >> 1) & 3;
  const int srow = tid >> 2, cslot = tid & 3;
  const int gc = cslot ^ ((srow >> 1) & 3);
  const int bh = blockIdx.y, b = bh >> 4, h = bh & 15;
  const int q0 = blockIdx.x << 7;

  const u16* qbase = QH + (size_t)bh * SEQ * DHEAD;
  const u16* kbase = KH + (size_t)bh * SEQ * DHEAD;
  const u16* vbase = VT + (size_t)bh * DHEAD * SEQ;

  #pragma unroll
  for (int hh = 0; hh < 2; ++hh) {
    lds16(qbase + (size_t)(q0 + srow) * DHEAD + hh * 32 + gc * 8, &Qs[hh][tid * 8]);
    lds16(qbase + (size_t)(q0 + 64 + srow) * DHEAD + hh * 32 + gc * 8, &Qs[hh][2048 + tid * 8]);
  }

  float lsum[2][4] = {};
  f32x4 o[2][4] = {};

  for (int t0 = 0; t0 < SEQ; t0 += 64) {
    __syncthreads();  // prior-iter Ks/Vt reads done
    #pragma unroll
    for (int hh = 0; hh < 2; ++hh) {
      lds16(kbase + (size_t)(t0 + srow) * DHEAD + hh * 32 + gc * 8, &Ks[hh][tid * 8]);
      lds16(vbase + (size_t)srow * SEQ + t0 + hh * 32 + gc * 8, &Vt[hh][tid * 8]);
    }
    __syncthreads();  // staging (incl. Q on iter 0) visible

    // S = Q K^T (log2-domain)
    f32x4 s[2][4] = {};
    #pragma unroll
    for (int hh = 0; hh < 2; ++hh) {
      bf16x8 aq[2];
      #pragma unroll
      for (int i = 0; i < 2; ++i)
        aq[i] = *(const bf16x8*)&Qs[hh][(w * 32 + i * 16 + l15) * 32 + (quad ^ sw) * 8];
      #pragma unroll
      for (int j = 0; j < 4; ++j) {
        const bf16x8 bk = *(const bf16x8*)&Ks[hh][(j * 16 + l15) * 32 + (quad ^ sw) * 8];
        s[0][j] = MFMA16(aq[0], bk, s[0][j]);
        s[1][j] = MFMA16(aq[1], bk, s[1][j]);
      }
    }

    // P = exp2(S); accumulate per-lane row partial sums; store bf16 (permuted)
    #pragma unroll
    for (int i = 0; i < 2; ++i)
      #pragma unroll
      for (int r = 0; r < 4; ++r) {
        const float p0 = EXP2F(s[i][0][r]);
        const float p1 = EXP2F(s[i][1][r]);
        const float p2 = EXP2F(s[i][2][r]);
        const float p3 = EXP2F(s[i][3][r]);
        lsum[i][r] += (p0 + p1) + (p2 + p3);
        ushort4 pk;
        pk.x = f2bf(p0); pk.y = f2bf(p1); pk.z = f2bf(p2); pk.w = f2bf(p3);
        *(ushort4*)&Ps[(w * 32 + i * 16 + (quad << 2) + r) * 72 + l15 * 4] = pk;
      }
    // Ps rows are wave-private; compiler orders intra-wave LDS write->read.

    // O += P V   (keys permuted consistently in Ps and Vt)
    #pragma unroll
    for (int hh = 0; hh < 2; ++hh) {
      bf16x8 ap[2];
      #pragma unroll
      for (int i = 0; i < 2; ++i)
        ap[i] = *(const bf16x8*)&Ps[(w * 32 + i * 16 + l15) * 72 + hh * 32 + quad * 8];
      #pragma unroll
      for (int j = 0; j < 4; ++j) {
        const bf16x8 vb = *(const bf16x8*)&Vt[hh][(j * 16 + l15) * 32 + (quad ^ sw) * 8];
        o[0][j] = MFMA16(ap[0], vb, o[0][j]);
        o[1][j] = MFMA16(ap[1], vb, o[1][j]);
      }
    }
  }

  float inv[2][4];
  #pragma unroll
  for (int i = 0; i < 2; ++i)
    #pragma unroll
    for (int r = 0; r < 4; ++r) {
      float t = lsum[i][r];
      #pragma unroll
      for (int off = 1; off < 16; off <<= 1)
        t += __shfl_xor(t, off);
      inv[i][r] = 1.f / t;
    }

  #pragma unroll
  for (int i = 0; i < 2; ++i)
    #pragma unroll
    for (int j = 0; j < 4; ++j)
      #pragma unroll
      for (int r = 0; r < 4; ++r) {
        const int qrow = q0 + w * 32 + i * 16 + (quad << 2) + r;
        Hidden[((size_t)(b * SEQ + qrow)) * HID + h * DHEAD + j * 16 + l15] =
            f2bf(o[i][j][r] * inv[i][r]);
      }
}

extern "C" void kernel_launch(void* const* d_in, const int* in_sizes, int n_in,
                              void* d_out, int out_size, void* d_ws, size_t ws_size,
                              hipStream_t stream) {
  const float* q  = (const float*)d_in[0];
  const float* k  = (const float*)d_in[1];
  const float* v  = (const float*)d_in[2];
  const int* mask = (const int*)d_in[3];
  const float* wq = (const float*)d_in[4];
  const float* bq = (const float*)d_in[5];
  const float* wk = (const float*)d_in[6];
  const float* bk = (const float*)d_in[7];
  const float* wv = (const float*)d_in[8];
  const float* bv = (const float*)d_in[9];
  const float* wo = (const float*)d_in[10];
  const float* bo = (const float*)d_in[11];

  const size_t SEG = (size_t)MROWS * HID;   // 8388608
  const size_t WSEG = (size_t)HID * HID;    // 1048576
  const dim3 gq(MROWS / 128, HID / 128, 3); // fused QKV: 1536 blocks
  const dim3 go(MROWS / 128, HID / 128);
  const dim3 ga(SEQ / 128, BATCH * HEADS);  // 16 x 64

  const size_t planB_bytes = (4 * WSEG + 4 * SEG) * sizeof(u16);  // 75.5 MB
  if (ws_size >= planB_bytes) {
    // weights bf16-DMA, activations VALU-staged
    u16* wqb = (u16*)d_ws;
    u16* wkb = wqb + WSEG;
    u16* wvb = wkb + WSEG;
    u16* wob = wvb + WSEG;
    u16* qh = wob + WSEG;
    u16* kh = qh + SEG;
    u16* vt = kh + SEG;
    u16* hidden = vt + SEG;

    cvt4_w<<<dim3(WSEG / 2048, 4), 256, 0, stream>>>(
        wq, wk, wv, wo, wqb, wkb, wvb, wob, (int)WSEG);
    gemm_qkv<true><<<gq, 256, 0, stream>>>(q, k, v, wqb, wkb, wvb,
                                           bq, bk, bv, mask, qh, kh, vt);
    attn_mfma<<<ga, 256, 0, stream>>>(qh, kh, vt, hidden);
    gemm_out<true><<<go, 256, 0, stream>>>(hidden, wob, bo, (float*)d_out);
  } else {
    // 64 MiB ws: everything VALU-staged from fp32
    u16* qh = (u16*)d_ws;
    u16* kh = qh + SEG;
    u16* vt = kh + SEG;
    u16* hidden = vt + SEG;

    gemm_qkv<false><<<gq, 256, 0, stream>>>(q, k, v, wq, wk, wv,
                                            bq, bk, bv, mask, qh, kh, vt);
    attn_mfma<<<ga, 256, 0, stream>>>(qh, kh, vt, hidden);
    gemm_out<false><<<go, 256, 0, stream>>>(hidden, wo, bo, (float*)d_out);
  }
}

// Round 5
// 377.916 us; speedup vs baseline: 5.4277x; 1.0938x over previous
//
#include <hip/hip_runtime.h>

#define BATCH 4
#define SEQ 2048
#define HEADS 16
#define DHEAD 64
#define HID 1024
#define MROWS (BATCH * SEQ)   // 8192
#define QSCALE 0.1803368801111092f   // 0.125 * log2(e): exp2 domain

typedef unsigned short u16;
typedef unsigned int u32;
typedef __attribute__((ext_vector_type(4))) float f32x4;
typedef __attribute__((ext_vector_type(8))) short bf16x8;

#define MFMA16(a, b, c) __builtin_amdgcn_mfma_f32_16x16x32_bf16((a), (b), (c), 0, 0, 0)
#define EXP2F(x) __builtin_amdgcn_exp2f(x)

// f32 -> bf16 round-to-nearest-even (finite inputs)
__device__ __forceinline__ u16 f2bf(float f) {
  union { float f; u32 i; } x; x.f = f;
  u32 r = x.i + 0x7fffu + ((x.i >> 16) & 1u);
  return (u16)(r >> 16);
}

// async global->LDS, 16 B/lane.  LDS dest must be wave-uniform base + lane*16.
__device__ __forceinline__ void lds16(const u16* g, u16* s) {
  __builtin_amdgcn_global_load_lds(
      (const __attribute__((address_space(1))) void*)g,
      (__attribute__((address_space(3))) void*)s, 16, 0, 0);
}

// VALU staging: 8 fp32 -> 8 bf16 (fallback paths + cvt kernel)
__device__ __forceinline__ void stage8f(const float* __restrict__ g, u16* s) {
  const float4 a = *(const float4*)g;
  const float4 b = *(const float4*)(g + 4);
  ushort4 lo, hi;
  lo.x = f2bf(a.x); lo.y = f2bf(a.y); lo.z = f2bf(a.z); lo.w = f2bf(a.w);
  hi.x = f2bf(b.x); hi.y = f2bf(b.y); hi.z = f2bf(b.z); hi.w = f2bf(b.w);
  *(ushort4*)s = lo;
  *(ushort4*)(s + 4) = hi;
}

// fp32 -> bf16 for up to 7 tensors in one launch.
// y(+yoff)=0..2: activations (n = SEG).  y=3: the 4 weights, packed as one
// 4*WSEG range (WSEG = 1<<20; j = i>>20 selects the tensor).
struct CvtArgs {
  const float* src[7];
  u16* dst[7];
};
__global__ __launch_bounds__(256) void cvt7(CvtArgs args, int yoff, int nact) {
  const int y = blockIdx.y + yoff;
  const int i = (blockIdx.x * 256 + threadIdx.x) * 8;
  if (y < 3) {
    if (i < nact) stage8f(args.src[y] + i, args.dst[y] + i);
  } else {
    if (i < 4 * (1 << 20)) {
      const int j = i >> 20, off = i & ((1 << 20) - 1);
      stage8f(args.src[3 + j] + off, args.dst[3 + j] + off);
    }
  }
}

// 128x128x(BK=32) MFMA GEMM core: C = A[M,K] @ W[N,K]^T, fp32 accum.
// ADMA/BDMA=1: operand bf16, global_load_lds; =0: fp32, VALU convert-stage.
// LDS chunk-slot XOR swizzle (slot = chunk ^ ((row>>1)&3)) -> conflict-free
// ds_read_b128 fragments while keeping the global_load_lds lane->slot contract.
template<bool ADMA, bool BDMA>
__device__ __forceinline__ void gemm_core(
    const void* __restrict__ Av, const void* __restrict__ Wv,
    int tid, int m0, int n0, u16* As, u16* Bs, f32x4 (&acc)[4][4])
{
  const int srow = tid >> 2, cslot = tid & 3;
  const int gc = cslot ^ ((srow >> 1) & 3);   // swizzled global chunk
  const int w = tid >> 6, l = tid & 63;
  const int quad = l >> 4, l15 = l & 15;
  const int sw = (l15 >> 1) & 3;
  const int wm = (w & 1) << 6, wn = (w >> 1) << 6;

  for (int k0 = 0; k0 < HID; k0 += 32) {
    if (ADMA) {
      const u16* ag = (const u16*)Av + (size_t)(m0 + srow) * HID + k0 + gc * 8;
      lds16(ag, &As[tid * 8]);
      lds16(ag + (size_t)64 * HID, &As[2048 + tid * 8]);
    } else {
      const float* ag = (const float*)Av + (size_t)(m0 + srow) * HID + k0 + gc * 8;
      stage8f(ag, &As[srow * 32 + cslot * 8]);
      stage8f(ag + (size_t)64 * HID, &As[(64 + srow) * 32 + cslot * 8]);
    }
    if (BDMA) {
      const u16* bg = (const u16*)Wv + (size_t)(n0 + srow) * HID + k0 + gc * 8;
      lds16(bg, &Bs[tid * 8]);
      lds16(bg + (size_t)64 * HID, &Bs[2048 + tid * 8]);
    } else {
      const float* bg = (const float*)Wv + (size_t)(n0 + srow) * HID + k0 + gc * 8;
      stage8f(bg, &Bs[srow * 32 + cslot * 8]);
      stage8f(bg + (size_t)64 * HID, &Bs[(64 + srow) * 32 + cslot * 8]);
    }
    __syncthreads();

    bf16x8 a[4], b[4];
    #pragma unroll
    for (int i = 0; i < 4; ++i)
      a[i] = *(const bf16x8*)&As[(wm + i * 16 + l15) * 32 + (quad ^ sw) * 8];
    #pragma unroll
    for (int j = 0; j < 4; ++j)
      b[j] = *(const bf16x8*)&Bs[(wn + j * 16 + l15) * 32 + (quad ^ sw) * 8];
    #pragma unroll
    for (int i = 0; i < 4; ++i)
      #pragma unroll
      for (int j = 0; j < 4; ++j)
        acc[i][j] = MFMA16(a[i], b[j], acc[i][j]);
    __syncthreads();
  }
}

// Fused QKV projection.  blockIdx.z selects q/k/v.  Epilogues:
//  z=0 (Q): *QSCALE and *mask(query row) -> masked rows produce logits 0.
//  z=1 (K): plain bf16 [bh][s][64].
//  z=2 (V): bf16 [bh][d][s], keys PERMUTED within each 64-group
//           (key s0 -> slot (s0&15)*4 + (s0>>4)) to match attention P-layout.
template<bool ADMA, bool BDMA>
__global__ __launch_bounds__(256) void gemm_qkv(
    const void* __restrict__ xq, const void* __restrict__ xk,
    const void* __restrict__ xv,
    const void* __restrict__ wqv, const void* __restrict__ wkv,
    const void* __restrict__ wvv,
    const float* __restrict__ bq, const float* __restrict__ bk,
    const float* __restrict__ bv, const int* __restrict__ Mask,
    u16* __restrict__ qh, u16* __restrict__ kh, u16* __restrict__ vt)
{
  __shared__ u16 As[128 * 32];
  __shared__ u16 Bs[128 * 32];
  const int z = blockIdx.z;
  const void* A = (z == 0) ? xq : (z == 1) ? xk : xv;
  const void* W = (z == 0) ? wqv : (z == 1) ? wkv : wvv;
  const float* Bias = (z == 0) ? bq : (z == 1) ? bk : bv;

  const int tid = threadIdx.x;
  const int m0 = blockIdx.x << 7, n0 = blockIdx.y << 7;
  f32x4 acc[4][4] = {};
  gemm_core<ADMA, BDMA>(A, W, tid, m0, n0, As, Bs, acc);

  const int w = tid >> 6, l = tid & 63;
  const int quad = l >> 4, l15 = l & 15;
  const int wm = (w & 1) << 6, wn = (w >> 1) << 6;

  if (z <= 1) {
    u16* Out = (z == 0) ? qh : kh;
    #pragma unroll
    for (int i = 0; i < 4; ++i) {
      float fl[4];
      #pragma unroll
      for (int r = 0; r < 4; ++r) {
        const int m = m0 + wm + i * 16 + (quad << 2) + r;
        fl[r] = (z == 0) ? (Mask[m] ? QSCALE : 0.f) : 1.f;
      }
      #pragma unroll
      for (int j = 0; j < 4; ++j) {
        const int n = n0 + wn + j * 16 + l15;
        const float bias = Bias[n];
        const int h = n >> 6, d = n & 63;
        #pragma unroll
        for (int r = 0; r < 4; ++r) {
          const int m = m0 + wm + i * 16 + (quad << 2) + r;
          const int bb = m >> 11, s = m & (SEQ - 1);
          Out[((size_t)(bb * HEADS + h) * SEQ + s) * DHEAD + d] =
              f2bf((acc[i][j][r] + bias) * fl[r]);
        }
      }
    }
  } else {
    const int sblk = (m0 + wm) & (SEQ - 1);
    const int bb = (m0 + wm) >> 11;
    #pragma unroll
    for (int j = 0; j < 4; ++j) {
      const int n = n0 + wn + j * 16 + l15;
      const float bias = Bias[n];
      const int h = n >> 6, d = n & 63;
      u16* base = vt + ((size_t)(bb * HEADS + h) * DHEAD + d) * SEQ + sblk;
      #pragma unroll
      for (int r = 0; r < 4; ++r) {
        ushort4 pk;
        pk.x = f2bf(acc[0][j][r] + bias);
        pk.y = f2bf(acc[1][j][r] + bias);
        pk.z = f2bf(acc[2][j][r] + bias);
        pk.w = f2bf(acc[3][j][r] + bias);
        *(ushort4*)(base + ((quad << 2) + r) * 4) = pk;
      }
    }
  }
}

// Output projection: fp32 out = hidden(bf16) @ wo^T + bo
template<bool BDMA>
__global__ __launch_bounds__(256) void gemm_out(
    const u16* __restrict__ hidden, const void* __restrict__ wov,
    const float* __restrict__ bo, float* __restrict__ Out)
{
  __shared__ u16 As[128 * 32];
  __shared__ u16 Bs[128 * 32];
  const int tid = threadIdx.x;
  const int m0 = blockIdx.x << 7, n0 = blockIdx.y << 7;
  f32x4 acc[4][4] = {};
  gemm_core<true, BDMA>(hidden, wov, tid, m0, n0, As, Bs, acc);

  const int w = tid >> 6, l = tid & 63;
  const int quad = l >> 4, l15 = l & 15;
  const int wm = (w & 1) << 6, wn = (w >> 1) << 6;
  #pragma unroll
  for (int j = 0; j < 4; ++j) {
    const int n = n0 + wn + j * 16 + l15;
    const float bias = bo[n];
    #pragma unroll
    for (int i = 0; i < 4; ++i) {
      const int mb = m0 + wm + i * 16 + (quad << 2);
      #pragma unroll
      for (int r = 0; r < 4; ++r)
        Out[(size_t)(mb + r) * HID + n] = acc[i][j][r] + bias;
    }
  }
}

// Flash attention, no-max softmax (scores bounded; masked rows pre-zeroed in Q
// so exp2(0)=1 -> uniform == reference).  128 queries/block, 4 waves of 32x64.
// Q fragments hoisted to registers (loop-invariant -> -4 b128 LDS reads/iter).
// P stored [q][p] (p = l15*4+j), pad 72; Vt key-permuted to match.
__global__ __launch_bounds__(256) void attn_mfma(
    const u16* __restrict__ QH, const u16* __restrict__ KH,
    const u16* __restrict__ VT, u16* __restrict__ Hidden)
{
  __shared__ u16 Qs[2][128 * 32];
  __shared__ u16 Ks[2][64 * 32];
  __shared__ u16 Vt[2][64 * 32];
  __shared__ u16 Ps[128 * 72];

  const int tid = threadIdx.x;
  const int w = tid >> 6, l = tid & 63;
  const int quad = l >> 4, l15 = l & 15;
  const int sw = (l15 >> 1) & 3;
  const int srow = tid >> 2, cslot = tid & 3;
  const int gc = cslot ^ ((srow >> 1) & 3);
  const int bh = blockIdx.y, b = bh >> 4, h = bh & 15;
  const int q0 = blockIdx.x << 7;

  const u16* qbase = QH + (size_t)bh * SEQ * DHEAD;
  const u16* kbase = KH + (size_t)bh * SEQ * DHEAD;
  const u16* vbase = VT + (size_t)bh * DHEAD * SEQ;

  #pragma unroll
  for (int hh = 0; hh < 2; ++hh) {
    lds16(qbase + (size_t)(q0 + srow) * DHEAD + hh * 32 + gc * 8, &Qs[hh][tid * 8]);
    lds16(qbase + (size_t)(q0 + 64 + srow) * DHEAD + hh * 32 + gc * 8, &Qs[hh][2048 + tid * 8]);
  }
  __syncthreads();  // Q staged (drains vmcnt)

  bf16x8 aq[2][2];
  #pragma unroll
  for (int hh = 0; hh < 2; ++hh)
    #pragma unroll
    for (int i = 0; i < 2; ++i)
      aq[hh][i] = *(const bf16x8*)&Qs[hh][(w * 32 + i * 16 + l15) * 32 + (quad ^ sw) * 8];

  float lsum[2][4] = {};
  f32x4 o[2][4] = {};

  for (int t0 = 0; t0 < SEQ; t0 += 64) {
    __syncthreads();  // prior-iter Ks/Vt reads done
    #pragma unroll
    for (int hh = 0; hh < 2; ++hh) {
      lds16(kbase + (size_t)(t0 + srow) * DHEAD + hh * 32 + gc * 8, &Ks[hh][tid * 8]);
      lds16(vbase + (size_t)srow * SEQ + t0 + hh * 32 + gc * 8, &Vt[hh][tid * 8]);
    }
    __syncthreads();  // staging visible

    // S = Q K^T (log2-domain)
    f32x4 s[2][4] = {};
    #pragma unroll
    for (int hh = 0; hh < 2; ++hh)
      #pragma unroll
      for (int j = 0; j < 4; ++j) {
        const bf16x8 bk = *(const bf16x8*)&Ks[hh][(j * 16 + l15) * 32 + (quad ^ sw) * 8];
        s[0][j] = MFMA16(aq[hh][0], bk, s[0][j]);
        s[1][j] = MFMA16(aq[hh][1], bk, s[1][j]);
      }

    // P = exp2(S); per-lane row partial sums; store bf16 (key-permuted)
    #pragma unroll
    for (int i = 0; i < 2; ++i)
      #pragma unroll
      for (int r = 0; r < 4; ++r) {
        const float p0 = EXP2F(s[i][0][r]);
        const float p1 = EXP2F(s[i][1][r]);
        const float p2 = EXP2F(s[i][2][r]);
        const float p3 = EXP2F(s[i][3][r]);
        lsum[i][r] += (p0 + p1) + (p2 + p3);
        ushort4 pk;
        pk.x = f2bf(p0); pk.y = f2bf(p1); pk.z = f2bf(p2); pk.w = f2bf(p3);
        *(ushort4*)&Ps[(w * 32 + i * 16 + (quad << 2) + r) * 72 + l15 * 4] = pk;
      }
    // Ps rows wave-private: intra-wave LDS write->read ordering is enforced.

    // O += P V
    #pragma unroll
    for (int hh = 0; hh < 2; ++hh) {
      bf16x8 ap[2];
      #pragma unroll
      for (int i = 0; i < 2; ++i)
        ap[i] = *(const bf16x8*)&Ps[(w * 32 + i * 16 + l15) * 72 + hh * 32 + quad * 8];
      #pragma unroll
      for (int j = 0; j < 4; ++j) {
        const bf16x8 vb = *(const bf16x8*)&Vt[hh][(j * 16 + l15) * 32 + (quad ^ sw) * 8];
        o[0][j] = MFMA16(ap[0], vb, o[0][j]);
        o[1][j] = MFMA16(ap[1], vb, o[1][j]);
      }
    }
  }

  float inv[2][4];
  #pragma unroll
  for (int i = 0; i < 2; ++i)
    #pragma unroll
    for (int r = 0; r < 4; ++r) {
      float t = lsum[i][r];
      #pragma unroll
      for (int off = 1; off < 16; off <<= 1)
        t += __shfl_xor(t, off);
      inv[i][r] = 1.f / t;
    }

  #pragma unroll
  for (int i = 0; i < 2; ++i)
    #pragma unroll
    for (int j = 0; j < 4; ++j)
      #pragma unroll
      for (int r = 0; r < 4; ++r) {
        const int qrow = q0 + w * 32 + i * 16 + (quad << 2) + r;
        Hidden[((size_t)(b * SEQ + qrow)) * HID + h * DHEAD + j * 16 + l15] =
            f2bf(o[i][j][r] * inv[i][r]);
      }
}

extern "C" void kernel_launch(void* const* d_in, const int* in_sizes, int n_in,
                              void* d_out, int out_size, void* d_ws, size_t ws_size,
                              hipStream_t stream) {
  const float* q  = (const float*)d_in[0];
  const float* k  = (const float*)d_in[1];
  const float* v  = (const float*)d_in[2];
  const int* mask = (const int*)d_in[3];
  const float* wq = (const float*)d_in[4];
  const float* bq = (const float*)d_in[5];
  const float* wk = (const float*)d_in[6];
  const float* bk = (const float*)d_in[7];
  const float* wv = (const float*)d_in[8];
  const float* bv = (const float*)d_in[9];
  const float* wo = (const float*)d_in[10];
  const float* bo = (const float*)d_in[11];

  const size_t SEG = (size_t)MROWS * HID;   // 8388608
  const size_t WSEG = (size_t)HID * HID;    // 1048576 = 1<<20
  const dim3 gq(MROWS / 128, HID / 128, 3); // fused QKV: 1536 blocks
  const dim3 go(MROWS / 128, HID / 128);
  const dim3 ga(SEQ / 128, BATCH * HEADS);  // 16 x 64

  const size_t planFULL = (6 * SEG + 4 * WSEG) * sizeof(u16);  // ~104 MB
  const size_t planMID  = (4 * SEG + 4 * WSEG) * sizeof(u16);  // ~75.5 MB

  if (ws_size >= planFULL) {
    // FULL: everything bf16, all GEMM operands on the global_load_lds path.
    // hidden aliases qb (dead after gemm_qkv).
    u16* qb  = (u16*)d_ws;
    u16* kb  = qb + SEG;
    u16* vb  = kb + SEG;
    u16* qh  = vb + SEG;
    u16* kh  = qh + SEG;
    u16* vt  = kh + SEG;
    u16* wqb = vt + SEG;
    u16* wkb = wqb + WSEG;
    u16* wvb = wkb + WSEG;
    u16* wob = wvb + WSEG;
    u16* hidden = qb;  // alias

    CvtArgs ca;
    ca.src[0] = q;  ca.dst[0] = qb;
    ca.src[1] = k;  ca.dst[1] = kb;
    ca.src[2] = v;  ca.dst[2] = vb;
    ca.src[3] = wq; ca.dst[3] = wqb;
    ca.src[4] = wk; ca.dst[4] = wkb;
    ca.src[5] = wv; ca.dst[5] = wvb;
    ca.src[6] = wo; ca.dst[6] = wob;
    cvt7<<<dim3(SEG / 2048, 4), 256, 0, stream>>>(ca, 0, (int)SEG);

    gemm_qkv<true, true><<<gq, 256, 0, stream>>>(qb, kb, vb, wqb, wkb, wvb,
                                                 bq, bk, bv, mask, qh, kh, vt);
    attn_mfma<<<ga, 256, 0, stream>>>(qh, kh, vt, hidden);
    gemm_out<true><<<go, 256, 0, stream>>>(hidden, wob, bo, (float*)d_out);
  } else if (ws_size >= planMID) {
    // MID: weights bf16-DMA, fp32 activations VALU-staged
    u16* wqb = (u16*)d_ws;
    u16* wkb = wqb + WSEG;
    u16* wvb = wkb + WSEG;
    u16* wob = wvb + WSEG;
    u16* qh = wob + WSEG;
    u16* kh = qh + SEG;
    u16* vt = kh + SEG;
    u16* hidden = vt + SEG;

    CvtArgs ca;
    ca.src[0] = ca.src[1] = ca.src[2] = q;  // unused slots
    ca.dst[0] = ca.dst[1] = ca.dst[2] = wqb;
    ca.src[3] = wq; ca.dst[3] = wqb;
    ca.src[4] = wk; ca.dst[4] = wkb;
    ca.src[5] = wv; ca.dst[5] = wvb;
    ca.src[6] = wo; ca.dst[6] = wob;
    cvt7<<<dim3(4 * WSEG / 2048, 1), 256, 0, stream>>>(ca, 3, 0);

    gemm_qkv<false, true><<<gq, 256, 0, stream>>>(q, k, v, wqb, wkb, wvb,
                                                  bq, bk, bv, mask, qh, kh, vt);
    attn_mfma<<<ga, 256, 0, stream>>>(qh, kh, vt, hidden);
    gemm_out<true><<<go, 256, 0, stream>>>(hidden, wob, bo, (float*)d_out);
  } else {
    // LOW: 64 MiB ws, all fp32 operands VALU-staged
    u16* qh = (u16*)d_ws;
    u16* kh = qh + SEG;
    u16* vt = kh + SEG;
    u16* hidden = vt + SEG;

    gemm_qkv<false, false><<<gq, 256, 0, stream>>>(q, k, v, wq, wk, wv,
                                                   bq, bk, bv, mask, qh, kh, vt);
    attn_mfma<<<ga, 256, 0, stream>>>(qh, kh, vt, hidden);
    gemm_out<false><<<go, 256, 0, stream>>>(hidden, wo, bo, (float*)d_out);
  }
}

// Round 6
// 358.874 us; speedup vs baseline: 5.7157x; 1.0531x over previous
//
#include <hip/hip_runtime.h>

#define BATCH 4
#define SEQ 2048
#define HEADS 16
#define DHEAD 64
#define HID 1024
#define MROWS (BATCH * SEQ)   // 8192
#define QSCALE 0.1803368801111092f   // 0.125 * log2(e): exp2 domain

typedef unsigned short u16;
typedef unsigned int u32;
typedef __attribute__((ext_vector_type(4))) float f32x4;
typedef __attribute__((ext_vector_type(8))) short bf16x8;

#define MFMA16(a, b, c) __builtin_amdgcn_mfma_f32_16x16x32_bf16((a), (b), (c), 0, 0, 0)
#define EXP2F(x) __builtin_amdgcn_exp2f(x)

// f32 -> bf16 round-to-nearest-even (finite inputs)
__device__ __forceinline__ u16 f2bf(float f) {
  union { float f; u32 i; } x; x.f = f;
  u32 r = x.i + 0x7fffu + ((x.i >> 16) & 1u);
  return (u16)(r >> 16);
}

// async global->LDS, 16 B/lane.  LDS dest must be wave-uniform base + lane*16.
__device__ __forceinline__ void lds16(const u16* g, u16* s) {
  __builtin_amdgcn_global_load_lds(
      (const __attribute__((address_space(1))) void*)g,
      (__attribute__((address_space(3))) void*)s, 16, 0, 0);
}

// VALU staging: 8 fp32 -> 8 bf16 (fallback paths + cvt kernel)
__device__ __forceinline__ void stage8f(const float* __restrict__ g, u16* s) {
  const float4 a = *(const float4*)g;
  const float4 b = *(const float4*)(g + 4);
  ushort4 lo, hi;
  lo.x = f2bf(a.x); lo.y = f2bf(a.y); lo.z = f2bf(a.z); lo.w = f2bf(a.w);
  hi.x = f2bf(b.x); hi.y = f2bf(b.y); hi.z = f2bf(b.z); hi.w = f2bf(b.w);
  *(ushort4*)s = lo;
  *(ushort4*)(s + 4) = hi;
}

// fp32 -> bf16 for up to 7 tensors in one launch.
// y(+yoff)=0..2: activations (n = SEG).  y=3: the 4 weights, packed as one
// 4*WSEG range (WSEG = 1<<20; j = i>>20 selects the tensor).
struct CvtArgs {
  const float* src[7];
  u16* dst[7];
};
__global__ __launch_bounds__(256) void cvt7(CvtArgs args, int yoff, int nact) {
  const int y = blockIdx.y + yoff;
  const int i = (blockIdx.x * 256 + threadIdx.x) * 8;
  if (y < 3) {
    if (i < nact) stage8f(args.src[y] + i, args.dst[y] + i);
  } else {
    if (i < 4 * (1 << 20)) {
      const int j = i >> 20, off = i & ((1 << 20) - 1);
      stage8f(args.src[3 + j] + off, args.dst[3 + j] + off);
    }
  }
}

// 128x128x(BK=32) MFMA GEMM core: C = A[M,K] @ W[N,K]^T, fp32 accum.
// ADMA/BDMA=1: operand bf16, global_load_lds; =0: fp32, VALU convert-stage.
// LDS chunk-slot XOR swizzle (slot = chunk ^ ((row>>1)&3)) -> conflict-free
// ds_read_b128 fragments while keeping the global_load_lds lane->slot contract.
template<bool ADMA, bool BDMA>
__device__ __forceinline__ void gemm_core(
    const void* __restrict__ Av, const void* __restrict__ Wv,
    int tid, int m0, int n0, u16* As, u16* Bs, f32x4 (&acc)[4][4])
{
  const int srow = tid >> 2, cslot = tid & 3;
  const int gc = cslot ^ ((srow >> 1) & 3);   // swizzled global chunk
  const int w = tid >> 6, l = tid & 63;
  const int quad = l >> 4, l15 = l & 15;
  const int sw = (l15 >> 1) & 3;
  const int wm = (w & 1) << 6, wn = (w >> 1) << 6;

  for (int k0 = 0; k0 < HID; k0 += 32) {
    if (ADMA) {
      const u16* ag = (const u16*)Av + (size_t)(m0 + srow) * HID + k0 + gc * 8;
      lds16(ag, &As[tid * 8]);
      lds16(ag + (size_t)64 * HID, &As[2048 + tid * 8]);
    } else {
      const float* ag = (const float*)Av + (size_t)(m0 + srow) * HID + k0 + gc * 8;
      stage8f(ag, &As[srow * 32 + cslot * 8]);
      stage8f(ag + (size_t)64 * HID, &As[(64 + srow) * 32 + cslot * 8]);
    }
    if (BDMA) {
      const u16* bg = (const u16*)Wv + (size_t)(n0 + srow) * HID + k0 + gc * 8;
      lds16(bg, &Bs[tid * 8]);
      lds16(bg + (size_t)64 * HID, &Bs[2048 + tid * 8]);
    } else {
      const float* bg = (const float*)Wv + (size_t)(n0 + srow) * HID + k0 + gc * 8;
      stage8f(bg, &Bs[srow * 32 + cslot * 8]);
      stage8f(bg + (size_t)64 * HID, &Bs[(64 + srow) * 32 + cslot * 8]);
    }
    __syncthreads();

    bf16x8 a[4], b[4];
    #pragma unroll
    for (int i = 0; i < 4; ++i)
      a[i] = *(const bf16x8*)&As[(wm + i * 16 + l15) * 32 + (quad ^ sw) * 8];
    #pragma unroll
    for (int j = 0; j < 4; ++j)
      b[j] = *(const bf16x8*)&Bs[(wn + j * 16 + l15) * 32 + (quad ^ sw) * 8];
    #pragma unroll
    for (int i = 0; i < 4; ++i)
      #pragma unroll
      for (int j = 0; j < 4; ++j)
        acc[i][j] = MFMA16(a[i], b[j], acc[i][j]);
    __syncthreads();
  }
}

// Fused QKV projection.  blockIdx.z selects q/k/v.  Epilogues:
//  z=0 (Q): *QSCALE and *mask(query row) -> masked rows produce logits 0.
//  z=1 (K): plain bf16 [bh][s][64].
//  z=2 (V): bf16 [bh][d][s], keys PERMUTED within each 64-group
//           (key s0 -> slot (s0&15)*4 + (s0>>4)) to match attention P-layout.
template<bool ADMA, bool BDMA>
__global__ __launch_bounds__(256) void gemm_qkv(
    const void* __restrict__ xq, const void* __restrict__ xk,
    const void* __restrict__ xv,
    const void* __restrict__ wqv, const void* __restrict__ wkv,
    const void* __restrict__ wvv,
    const float* __restrict__ bq, const float* __restrict__ bk,
    const float* __restrict__ bv, const int* __restrict__ Mask,
    u16* __restrict__ qh, u16* __restrict__ kh, u16* __restrict__ vt)
{
  __shared__ u16 As[128 * 32];
  __shared__ u16 Bs[128 * 32];
  const int z = blockIdx.z;
  const void* A = (z == 0) ? xq : (z == 1) ? xk : xv;
  const void* W = (z == 0) ? wqv : (z == 1) ? wkv : wvv;
  const float* Bias = (z == 0) ? bq : (z == 1) ? bk : bv;

  const int tid = threadIdx.x;
  const int m0 = blockIdx.x << 7, n0 = blockIdx.y << 7;
  f32x4 acc[4][4] = {};
  gemm_core<ADMA, BDMA>(A, W, tid, m0, n0, As, Bs, acc);

  const int w = tid >> 6, l = tid & 63;
  const int quad = l >> 4, l15 = l & 15;
  const int wm = (w & 1) << 6, wn = (w >> 1) << 6;

  if (z <= 1) {
    u16* Out = (z == 0) ? qh : kh;
    #pragma unroll
    for (int i = 0; i < 4; ++i) {
      float fl[4];
      #pragma unroll
      for (int r = 0; r < 4; ++r) {
        const int m = m0 + wm + i * 16 + (quad << 2) + r;
        fl[r] = (z == 0) ? (Mask[m] ? QSCALE : 0.f) : 1.f;
      }
      #pragma unroll
      for (int j = 0; j < 4; ++j) {
        const int n = n0 + wn + j * 16 + l15;
        const float bias = Bias[n];
        const int h = n >> 6, d = n & 63;
        #pragma unroll
        for (int r = 0; r < 4; ++r) {
          const int m = m0 + wm + i * 16 + (quad << 2) + r;
          const int bb = m >> 11, s = m & (SEQ - 1);
          Out[((size_t)(bb * HEADS + h) * SEQ + s) * DHEAD + d] =
              f2bf((acc[i][j][r] + bias) * fl[r]);
        }
      }
    }
  } else {
    const int sblk = (m0 + wm) & (SEQ - 1);
    const int bb = (m0 + wm) >> 11;
    #pragma unroll
    for (int j = 0; j < 4; ++j) {
      const int n = n0 + wn + j * 16 + l15;
      const float bias = Bias[n];
      const int h = n >> 6, d = n & 63;
      u16* base = vt + ((size_t)(bb * HEADS + h) * DHEAD + d) * SEQ + sblk;
      #pragma unroll
      for (int r = 0; r < 4; ++r) {
        ushort4 pk;
        pk.x = f2bf(acc[0][j][r] + bias);
        pk.y = f2bf(acc[1][j][r] + bias);
        pk.z = f2bf(acc[2][j][r] + bias);
        pk.w = f2bf(acc[3][j][r] + bias);
        *(ushort4*)(base + ((quad << 2) + r) * 4) = pk;
      }
    }
  }
}

// Output projection: fp32 out = hidden(bf16) @ wo^T + bo
template<bool BDMA>
__global__ __launch_bounds__(256) void gemm_out(
    const u16* __restrict__ hidden, const void* __restrict__ wov,
    const float* __restrict__ bo, float* __restrict__ Out)
{
  __shared__ u16 As[128 * 32];
  __shared__ u16 Bs[128 * 32];
  const int tid = threadIdx.x;
  const int m0 = blockIdx.x << 7, n0 = blockIdx.y << 7;
  f32x4 acc[4][4] = {};
  gemm_core<true, BDMA>(hidden, wov, tid, m0, n0, As, Bs, acc);

  const int w = tid >> 6, l = tid & 63;
  const int quad = l >> 4, l15 = l & 15;
  const int wm = (w & 1) << 6, wn = (w >> 1) << 6;
  #pragma unroll
  for (int j = 0; j < 4; ++j) {
    const int n = n0 + wn + j * 16 + l15;
    const float bias = bo[n];
    #pragma unroll
    for (int i = 0; i < 4; ++i) {
      const int mb = m0 + wm + i * 16 + (quad << 2);
      #pragma unroll
      for (int r = 0; r < 4; ++r)
        Out[(size_t)(mb + r) * HID + n] = acc[i][j][r] + bias;
    }
  }
}

// Flash attention, no-max softmax.  128-thread blocks (2 waves); each wave
// owns 64 queries (4 row-tiles of 16) x all 64 keys of the tile -> K/V LDS
// reads amortize over 2x queries vs the 32q/wave version (LDS-pipe bound).
// LDS 32 KB: Ps (128x64, XOR-chunk swizzled, padless) OVERLAYS Qs (Q lives in
// registers after init; rows are wave-private so no cross-wave hazard).
// XCD remap: bh = lin&63 -> all 16 q-tiles of a head on one XCD's L2.
__global__ __launch_bounds__(128, 2) void attn_mfma(
    const u16* __restrict__ QH, const u16* __restrict__ KH,
    const u16* __restrict__ VT, u16* __restrict__ Hidden)
{
  __shared__ u16 QP[128 * 64];     // 16 KB: Qs [2][128x32] then Ps [128][64]
  __shared__ u16 Ks[2][64 * 32];   // 8 KB
  __shared__ u16 Vt[2][64 * 32];   // 8 KB

  const int tid = threadIdx.x;     // 0..127
  const int w = tid >> 6, l = tid & 63;
  const int quad = l >> 4, l15 = l & 15;
  const int sw = (l15 >> 1) & 3;
  const int srow = tid >> 2, cslot = tid & 3;
  const int gc = cslot ^ ((srow >> 1) & 3);   // staging swizzle (global side)

  const int lin = blockIdx.y * 16 + blockIdx.x;
  const int bh = lin & 63, b = bh >> 4, h = bh & 15;
  const int q0 = (lin >> 6) << 7;

  const u16* qbase = QH + (size_t)bh * SEQ * DHEAD;
  const u16* kbase = KH + (size_t)bh * SEQ * DHEAD;
  const u16* vbase = VT + (size_t)bh * DHEAD * SEQ;

  // stage Q: Qs[hh] = QP + hh*4096, rows 0..127 x 32 u16 (gc-swizzled chunks)
  #pragma unroll
  for (int hh = 0; hh < 2; ++hh)
    #pragma unroll
    for (int part = 0; part < 4; ++part)
      lds16(qbase + (size_t)(q0 + part * 32 + srow) * DHEAD + hh * 32 + gc * 8,
            &QP[hh * 4096 + part * 1024 + tid * 8]);
  __syncthreads();  // drains vmcnt: Q visible

  // Q fragments -> registers (loop-invariant).  8 x b128 = 32 VGPRs.
  bf16x8 aq[2][4];
  #pragma unroll
  for (int hh = 0; hh < 2; ++hh)
    #pragma unroll
    for (int i = 0; i < 4; ++i)
      aq[hh][i] = *(const bf16x8*)
          &QP[hh * 4096 + (w * 64 + i * 16 + l15) * 32 + (quad ^ sw) * 8];

  float lsum[4][4] = {};
  f32x4 o[4][4] = {};

  for (int t0 = 0; t0 < SEQ; t0 += 64) {
    __syncthreads();  // prior-iter Ks/Vt reads (and init aq reads) done
    #pragma unroll
    for (int hh = 0; hh < 2; ++hh)
      #pragma unroll
      for (int part = 0; part < 2; ++part) {
        lds16(kbase + (size_t)(t0 + part * 32 + srow) * DHEAD + hh * 32 + gc * 8,
              &Ks[hh][part * 1024 + tid * 8]);
        lds16(vbase + (size_t)(part * 32 + srow) * SEQ + t0 + hh * 32 + gc * 8,
              &Vt[hh][part * 1024 + tid * 8]);
      }
    __syncthreads();  // staging visible

    // S = Q K^T (log2-domain), 32 MFMA, 8 Ks reads
    f32x4 s[4][4] = {};
    #pragma unroll
    for (int j = 0; j < 4; ++j)
      #pragma unroll
      for (int hh = 0; hh < 2; ++hh) {
        const bf16x8 bk = *(const bf16x8*)
            &Ks[hh][(j * 16 + l15) * 32 + (quad ^ sw) * 8];
        #pragma unroll
        for (int i = 0; i < 4; ++i)
          s[i][j] = MFMA16(aq[hh][i], bk, s[i][j]);
      }

    // P = exp2(S); per-lane row partials; store bf16 into swizzled Ps.
    // content chunk c = l15>>1 at slot c ^ (row&7); key perm p = l15*4+j.
    #pragma unroll
    for (int i = 0; i < 4; ++i)
      #pragma unroll
      for (int r = 0; r < 4; ++r) {
        const float p0 = EXP2F(s[i][0][r]);
        const float p1 = EXP2F(s[i][1][r]);
        const float p2 = EXP2F(s[i][2][r]);
        const float p3 = EXP2F(s[i][3][r]);
        lsum[i][r] += (p0 + p1) + (p2 + p3);
        const int row = w * 64 + i * 16 + (quad << 2) + r;
        const int cs = ((l15 >> 1) ^ (row & 7)) * 8 + (l15 & 1) * 4;
        ushort4 pk;
        pk.x = f2bf(p0); pk.y = f2bf(p1); pk.z = f2bf(p2); pk.w = f2bf(p3);
        *(ushort4*)&QP[row * 64 + cs] = pk;
      }
    // Ps rows wave-private: intra-wave LDS write->read ordering is enforced.

    // O += P V  (32 MFMA, 8 Ps + 8 Vt reads)
    #pragma unroll
    for (int hh = 0; hh < 2; ++hh) {
      bf16x8 ap[4];
      #pragma unroll
      for (int i = 0; i < 4; ++i) {
        const int row = w * 64 + i * 16 + l15;
        ap[i] = *(const bf16x8*)
            &QP[row * 64 + (((hh * 4 + quad) ^ (row & 7)) << 3)];
      }
      #pragma unroll
      for (int j = 0; j < 4; ++j) {
        const bf16x8 vb = *(const bf16x8*)
            &Vt[hh][(j * 16 + l15) * 32 + (quad ^ sw) * 8];
        #pragma unroll
        for (int i = 0; i < 4; ++i)
          o[i][j] = MFMA16(ap[i], vb, o[i][j]);
      }
    }
  }

  float inv[4][4];
  #pragma unroll
  for (int i = 0; i < 4; ++i)
    #pragma unroll
    for (int r = 0; r < 4; ++r) {
      float t = lsum[i][r];
      #pragma unroll
      for (int off = 1; off < 16; off <<= 1)
        t += __shfl_xor(t, off);
      inv[i][r] = 1.f / t;
    }

  #pragma unroll
  for (int i = 0; i < 4; ++i)
    #pragma unroll
    for (int j = 0; j < 4; ++j)
      #pragma unroll
      for (int r = 0; r < 4; ++r) {
        const int qrow = q0 + w * 64 + i * 16 + (quad << 2) + r;
        Hidden[((size_t)(b * SEQ + qrow)) * HID + h * DHEAD + j * 16 + l15] =
            f2bf(o[i][j][r] * inv[i][r]);
      }
}

extern "C" void kernel_launch(void* const* d_in, const int* in_sizes, int n_in,
                              void* d_out, int out_size, void* d_ws, size_t ws_size,
                              hipStream_t stream) {
  const float* q  = (const float*)d_in[0];
  const float* k  = (const float*)d_in[1];
  const float* v  = (const float*)d_in[2];
  const int* mask = (const int*)d_in[3];
  const float* wq = (const float*)d_in[4];
  const float* bq = (const float*)d_in[5];
  const float* wk = (const float*)d_in[6];
  const float* bk = (const float*)d_in[7];
  const float* wv = (const float*)d_in[8];
  const float* bv = (const float*)d_in[9];
  const float* wo = (const float*)d_in[10];
  const float* bo = (const float*)d_in[11];

  const size_t SEG = (size_t)MROWS * HID;   // 8388608
  const size_t WSEG = (size_t)HID * HID;    // 1048576 = 1<<20
  const dim3 gq(MROWS / 128, HID / 128, 3); // fused QKV: 1536 blocks
  const dim3 go(MROWS / 128, HID / 128);
  const dim3 ga(SEQ / 128, BATCH * HEADS);  // 16 x 64

  const size_t planFULL = (6 * SEG + 4 * WSEG) * sizeof(u16);  // ~104 MB
  const size_t planMID  = (4 * SEG + 4 * WSEG) * sizeof(u16);  // ~75.5 MB

  if (ws_size >= planFULL) {
    // FULL: everything bf16, all GEMM operands on the global_load_lds path.
    u16* qb  = (u16*)d_ws;
    u16* kb  = qb + SEG;
    u16* vb  = kb + SEG;
    u16* qh  = vb + SEG;
    u16* kh  = qh + SEG;
    u16* vt  = kh + SEG;
    u16* wqb = vt + SEG;
    u16* wkb = wqb + WSEG;
    u16* wvb = wkb + WSEG;
    u16* wob = wvb + WSEG;
    u16* hidden = qb;  // alias (qb dead after gemm_qkv)

    CvtArgs ca;
    ca.src[0] = q;  ca.dst[0] = qb;
    ca.src[1] = k;  ca.dst[1] = kb;
    ca.src[2] = v;  ca.dst[2] = vb;
    ca.src[3] = wq; ca.dst[3] = wqb;
    ca.src[4] = wk; ca.dst[4] = wkb;
    ca.src[5] = wv; ca.dst[5] = wvb;
    ca.src[6] = wo; ca.dst[6] = wob;
    cvt7<<<dim3(SEG / 2048, 4), 256, 0, stream>>>(ca, 0, (int)SEG);

    gemm_qkv<true, true><<<gq, 256, 0, stream>>>(qb, kb, vb, wqb, wkb, wvb,
                                                 bq, bk, bv, mask, qh, kh, vt);
    attn_mfma<<<ga, 128, 0, stream>>>(qh, kh, vt, hidden);
    gemm_out<true><<<go, 256, 0, stream>>>(hidden, wob, bo, (float*)d_out);
  } else if (ws_size >= planMID) {
    // MID: weights bf16-DMA, fp32 activations VALU-staged
    u16* wqb = (u16*)d_ws;
    u16* wkb = wqb + WSEG;
    u16* wvb = wkb + WSEG;
    u16* wob = wvb + WSEG;
    u16* qh = wob + WSEG;
    u16* kh = qh + SEG;
    u16* vt = kh + SEG;
    u16* hidden = vt + SEG;

    CvtArgs ca;
    ca.src[0] = ca.src[1] = ca.src[2] = q;  // unused slots
    ca.dst[0] = ca.dst[1] = ca.dst[2] = wqb;
    ca.src[3] = wq; ca.dst[3] = wqb;
    ca.src[4] = wk; ca.dst[4] = wkb;
    ca.src[5] = wv; ca.dst[5] = wvb;
    ca.src[6] = wo; ca.dst[6] = wob;
    cvt7<<<dim3(4 * WSEG / 2048, 1), 256, 0, stream>>>(ca, 3, 0);

    gemm_qkv<false, true><<<gq, 256, 0, stream>>>(q, k, v, wqb, wkb, wvb,
                                                  bq, bk, bv, mask, qh, kh, vt);
    attn_mfma<<<ga, 128, 0, stream>>>(qh, kh, vt, hidden);
    gemm_out<true><<<go, 256, 0, stream>>>(hidden, wob, bo, (float*)d_out);
  } else {
    // LOW: 64 MiB ws, all fp32 operands VALU-staged
    u16* qh = (u16*)d_ws;
    u16* kh = qh + SEG;
    u16* vt = kh + SEG;
    u16* hidden = vt + SEG;

    gemm_qkv<false, false><<<gq, 256, 0, stream>>>(q, k, v, wq, wk, wv,
                                                   bq, bk, bv, mask, qh, kh, vt);
    attn_mfma<<<ga, 128, 0, stream>>>(qh, kh, vt, hidden);
    gemm_out<false><<<go, 256, 0, stream>>>(hidden, wo, bo, (float*)d_out);
  }
}